// Round 1
// 3091.438 us; speedup vs baseline: 1.2936x; 1.2936x over previous
//
#include <hip/hip_runtime.h>
#include <math.h>

#define Tn   2048
#define Dn   2048
#define HQn  16
#define HKVn 8
#define HDn  128
#define NEXP 16
#define Fn   1024
#define FSn  2048
#define QKVN 4096
#define THETAf 500000.0f

typedef unsigned short u16;
typedef __attribute__((ext_vector_type(8))) short bf16x8;   // 8 bf16 in 4 VGPRs
typedef __attribute__((ext_vector_type(4))) float f32x4;    // MFMA 16x16 accumulator

// ---------------------------------------------------------------- helpers
// split fp32 -> bf16 hi + bf16 lo (RNE both). x ~= hi + lo to ~2^-17 rel.
__device__ __forceinline__ void split_bf16(float x, u16& h, u16& l)
{
    unsigned u = __float_as_uint(x);
    u16 hh = (u16)((u + 0x7fffu + ((u >> 16) & 1u)) >> 16);
    float hf = __uint_as_float((unsigned)hh << 16);
    float r = x - hf;                       // exact
    unsigned u2 = __float_as_uint(r);
    u16 ll = (u16)((u2 + 0x7fffu + ((u2 >> 16) & 1u)) >> 16);
    h = hh; l = ll;
}

// async global->LDS, 16B per lane. LDS dest is wave-uniform base + lane*16.
__device__ __forceinline__ void async16(u16* lds, const u16* g)
{
    __builtin_amdgcn_global_load_lds(
        (const __attribute__((address_space(1))) void*)(const void*)g,
        (__attribute__((address_space(3))) void*)(void*)lds, 16, 0, 0);
}

// ---------------------------------------------------------------- RMSNorm
__global__ __launch_bounds__(256) void rmsnorm_k(const float* __restrict__ x,
        const float* __restrict__ w, float* __restrict__ out)
{
    int t = blockIdx.x;
    const float4* row = (const float4*)(x + (size_t)t * Dn);
    const float4* wv  = (const float4*)w;
    int i = threadIdx.x;
    float4 v0 = row[i], v1 = row[i + 256];
    float ss = v0.x*v0.x + v0.y*v0.y + v0.z*v0.z + v0.w*v0.w
             + v1.x*v1.x + v1.y*v1.y + v1.z*v1.z + v1.w*v1.w;
    #pragma unroll
    for (int o = 32; o > 0; o >>= 1) ss += __shfl_down(ss, o, 64);
    __shared__ float wsum[4];
    if ((i & 63) == 0) wsum[i >> 6] = ss;
    __syncthreads();
    float tot = wsum[0] + wsum[1] + wsum[2] + wsum[3];
    float rs = rsqrtf(tot * (1.0f / Dn) + 1e-5f);
    float4 w0 = wv[i], w1 = wv[i + 256];
    float4 o0 = make_float4(v0.x*rs*w0.x, v0.y*rs*w0.y, v0.z*rs*w0.z, v0.w*rs*w0.w);
    float4 o1 = make_float4(v1.x*rs*w1.x, v1.y*rs*w1.y, v1.z*rs*w1.z, v1.w*rs*w1.w);
    float4* orow = (float4*)(out + (size_t)t * Dn);
    orow[i] = o0; orow[i + 256] = o1;
}

// ---------------------------------------------------------------- fp32 -> hi/lo bf16 (no transpose)
__global__ __launch_bounds__(256) void cvt_k(const float* __restrict__ x,
        u16* __restrict__ hi, u16* __restrict__ lo, int n4)
{
    int i = blockIdx.x * 256 + threadIdx.x;
    if (i >= n4) return;
    float4 v = ((const float4*)x)[i];
    ushort4 h, l;
    split_bf16(v.x, h.x, l.x);
    split_bf16(v.y, h.y, l.y);
    split_bf16(v.z, h.z, l.z);
    split_bf16(v.w, h.w, l.w);
    ((ushort4*)hi)[i] = h;
    ((ushort4*)lo)[i] = l;
}

// ---------------------------------------------------------------- fp32 B[K,N] -> hi/lo bf16 B^T[N,K]
// ldb = row stride of B (allows column-slicing wqkv). Output is [Nd_block][Kd] dense.
__global__ __launch_bounds__(256) void cvt_t_k(const float* __restrict__ B,
        u16* __restrict__ th, u16* __restrict__ tl, int Kd, int ldb)
{
    __shared__ float tile[32][33];
    int k0 = blockIdx.y << 5, n0 = blockIdx.x << 5;
    int tid = threadIdx.x;
    int c = tid & 31, r0 = (tid >> 5) << 2;
    #pragma unroll
    for (int i = 0; i < 4; ++i)
        tile[r0 + i][c] = B[(size_t)(k0 + r0 + i) * ldb + n0 + c];
    __syncthreads();
    int n = tid >> 3, kc = (tid & 7) << 2;
    ushort4 h, l;
    split_bf16(tile[kc + 0][n], h.x, l.x);
    split_bf16(tile[kc + 1][n], h.y, l.y);
    split_bf16(tile[kc + 2][n], h.z, l.z);
    split_bf16(tile[kc + 3][n], h.w, l.w);
    size_t ob = (size_t)(n0 + n) * Kd + k0 + kc;
    *(ushort4*)(th + ob) = h;
    *(ushort4*)(tl + ob) = l;
}

// ---------------------------------------------------------------- split-bf16 MFMA GEMM
// C[M,N](ldc) = Ah+Al [M,K] @ (Bh+Bl)^T where B given as B^T [N,K]  (+R).
// 128x128 tile, BK=32, 4 waves (2x2), each wave 64x64 = 4x4 frags of 16x16.
// 3 MFMAs per frag-pair: Ah*Bh + Ah*Bl + Al*Bh  (lo*lo dropped, ~2^-18).
template<bool RESID>
__global__ __launch_bounds__(256) void gemm_mfma_k(
        const u16* __restrict__ Ah, const u16* __restrict__ Al,
        const u16* __restrict__ Bh, const u16* __restrict__ Bl,
        const float* __restrict__ R, float* __restrict__ C,
        int K, int ldc)
{
    __shared__ u16 sAh[128 * 32], sAl[128 * 32], sBh[128 * 32], sBl[128 * 32];
    int tid  = threadIdx.x;
    int lane = tid & 63, w = tid >> 6;
    int wm = w >> 1, wn = w & 1;
    int bm0 = blockIdx.y << 7, bn0 = blockIdx.x << 7;
    int fr = lane & 15, kg = lane >> 4;
    f32x4 acc[4][4] = {};
    int rA = lane >> 2;              // row within a 16-row staging segment
    int co = (lane & 3) << 3;        // 8 u16 = 16B column chunk

    for (int k0 = 0; k0 < K; k0 += 32) {
        __syncthreads();             // protect LDS from prior iteration's readers
        #pragma unroll
        for (int t = 0; t < 2; ++t) {
            int s = (w << 1) + t;    // segment 0..7 (16 rows each)
            int r = (s << 4) + rA;
            size_t ga = (size_t)(bm0 + r) * K + k0 + co;
            size_t gb = (size_t)(bn0 + r) * K + k0 + co;
            int lofs = s << 9;       // s*512 u16 = s*1024B
            async16(sAh + lofs, Ah + ga);
            async16(sAl + lofs, Al + ga);
            async16(sBh + lofs, Bh + gb);
            async16(sBl + lofs, Bl + gb);
        }
        __syncthreads();             // drains vmcnt (compiler emits vmcnt(0) before barrier)

        bf16x8 ah[4], al[4], bh[4], bl[4];
        #pragma unroll
        for (int i = 0; i < 4; ++i) {
            int ar = (((wm << 6) + (i << 4) + fr) << 5) + (kg << 3);
            int bc = (((wn << 6) + (i << 4) + fr) << 5) + (kg << 3);
            ah[i] = *(const bf16x8*)&sAh[ar];
            al[i] = *(const bf16x8*)&sAl[ar];
            bh[i] = *(const bf16x8*)&sBh[bc];
            bl[i] = *(const bf16x8*)&sBl[bc];
        }
        #pragma unroll
        for (int i = 0; i < 4; ++i)
            #pragma unroll
            for (int j = 0; j < 4; ++j) {
                acc[i][j] = __builtin_amdgcn_mfma_f32_16x16x32_bf16(ah[i], bh[j], acc[i][j], 0, 0, 0);
                acc[i][j] = __builtin_amdgcn_mfma_f32_16x16x32_bf16(ah[i], bl[j], acc[i][j], 0, 0, 0);
                acc[i][j] = __builtin_amdgcn_mfma_f32_16x16x32_bf16(al[i], bh[j], acc[i][j], 0, 0, 0);
            }
    }

    // C/D layout (m89-verified): col = lane&15, row = (lane>>4)*4 + reg
    #pragma unroll
    for (int i = 0; i < 4; ++i) {
        int row0 = bm0 + (wm << 6) + (i << 4) + (kg << 2);
        #pragma unroll
        for (int j = 0; j < 4; ++j) {
            int col = bn0 + (wn << 6) + (j << 4) + fr;
            #pragma unroll
            for (int r = 0; r < 4; ++r) {
                size_t o = (size_t)(row0 + r) * ldc + col;
                C[o] = acc[i][j][r] + (RESID ? R[o] : 0.0f);
            }
        }
    }
}

// ---------------------------------------------------------------- RoPE (interleaved, 3-section mrope)
__global__ void rope_k(float* __restrict__ qkv, const int* __restrict__ pos)
{
    int t = blockIdx.x, hh = blockIdx.y, i = threadIdx.x;  // i = 0..63 freq pairs
    int sec = (i < 22) ? 0 : (i < 44 ? 1 : 2);
    float p = (float)pos[sec * Tn + t];
    float freq = powf(THETAf, -2.0f * (float)i / (float)HDn);
    float ang = p * freq;
    float s, c;
    sincosf(ang, &s, &c);
    float* base = qkv + (size_t)t * QKVN +
                  (hh < HQn ? hh * HDn : HQn * HDn + (hh - HQn) * HDn);
    float x1 = base[2*i], x2 = base[2*i+1];
    base[2*i]   = x1 * c - x2 * s;
    base[2*i+1] = x2 * c + x1 * s;
}

// ---------------------------------------------------------------- flash attention (causal, GQA)
#define QT 32
#define KT 32
#define HDP (HDn + 4)
__global__ __launch_bounds__(256) void attn_k(const float* __restrict__ qkv,
                                              float* __restrict__ attn)
{
    __shared__ float sQ[QT][HDP];
    __shared__ float sK[KT][HDP];
    __shared__ float sV[KT][HDP];
    __shared__ float sS[QT][KT + 1];
    __shared__ float sM[QT], sL[QT], sAl[QT];
    int hq = blockIdx.y;
    int q0 = blockIdx.x * QT;
    int kvh = hq >> 1;
    int tid = threadIdx.x;
    const float scale = 0.08838834764831845f;  // 128^-0.5
    #pragma unroll
    for (int l2 = 0; l2 < 4; ++l2) {
        int idx = tid + l2 * 256;
        int r = idx >> 5, c = (idx & 31) * 4;
        *(float4*)&sQ[r][c] =
            *(const float4*)(qkv + (size_t)(q0 + r) * QKVN + hq * HDn + c);
    }
    if (tid < QT) { sM[tid] = -1e30f; sL[tid] = 0.0f; }
    float acc[16];
    #pragma unroll
    for (int j = 0; j < 16; ++j) acc[j] = 0.0f;
    int q = tid & 31, g = tid >> 5;   // g = k-group (scores) / d-group (PV)
    int ntile = q0 / KT + 1;
    for (int it = 0; it < ntile; ++it) {
        int kt = it * KT;
        __syncthreads();
        #pragma unroll
        for (int l2 = 0; l2 < 4; ++l2) {
            int idx = tid + l2 * 256;
            int r = idx >> 5, c = (idx & 31) * 4;
            const float* kb = qkv + (size_t)(kt + r) * QKVN + HQn * HDn + kvh * HDn + c;
            *(float4*)&sK[r][c] = *(const float4*)kb;
            *(float4*)&sV[r][c] = *(const float4*)(kb + HKVn * HDn);
        }
        __syncthreads();
        float dots[4] = {0.f, 0.f, 0.f, 0.f};
        for (int d4 = 0; d4 < 32; ++d4) {
            float4 qv = *(float4*)&sQ[q][d4 * 4];
            #pragma unroll
            for (int kk = 0; kk < 4; ++kk) {
                float4 kv = *(float4*)&sK[g * 4 + kk][d4 * 4];
                dots[kk] += qv.x*kv.x + qv.y*kv.y + qv.z*kv.z + qv.w*kv.w;
            }
        }
        #pragma unroll
        for (int kk = 0; kk < 4; ++kk) {
            int kglob = kt + g * 4 + kk;
            sS[q][g * 4 + kk] = (kglob <= q0 + q) ? dots[kk] * scale : -1e30f;
        }
        __syncthreads();
        if (tid < QT) {
            float mold = sM[tid];
            float tm = mold;
            #pragma unroll
            for (int k = 0; k < KT; ++k) tm = fmaxf(tm, sS[tid][k]);
            float alpha = __expf(mold - tm);
            float lsum = 0.0f;
            #pragma unroll
            for (int k = 0; k < KT; ++k) {
                float pv = __expf(sS[tid][k] - tm);
                sS[tid][k] = pv;
                lsum += pv;
            }
            sM[tid] = tm;
            sL[tid] = sL[tid] * alpha + lsum;
            sAl[tid] = alpha;
        }
        __syncthreads();
        float alpha = sAl[q];
        #pragma unroll
        for (int j = 0; j < 16; ++j) acc[j] *= alpha;
        for (int k = 0; k < KT; ++k) {
            float pv = sS[q][k];
            const float* vb = &sV[k][g * 16];
            float4 v0 = *(float4*)(vb + 0), v1 = *(float4*)(vb + 4);
            float4 v2 = *(float4*)(vb + 8), v3 = *(float4*)(vb + 12);
            acc[0]  += pv*v0.x; acc[1]  += pv*v0.y; acc[2]  += pv*v0.z; acc[3]  += pv*v0.w;
            acc[4]  += pv*v1.x; acc[5]  += pv*v1.y; acc[6]  += pv*v1.z; acc[7]  += pv*v1.w;
            acc[8]  += pv*v2.x; acc[9]  += pv*v2.y; acc[10] += pv*v2.z; acc[11] += pv*v2.w;
            acc[12] += pv*v3.x; acc[13] += pv*v3.y; acc[14] += pv*v3.z; acc[15] += pv*v3.w;
        }
    }
    float linv = 1.0f / sL[q];
    float* ob = attn + (size_t)(q0 + q) * (HQn * HDn) + hq * HDn + g * 16;
    *(float4*)(ob + 0)  = make_float4(acc[0]*linv,  acc[1]*linv,  acc[2]*linv,  acc[3]*linv);
    *(float4*)(ob + 4)  = make_float4(acc[4]*linv,  acc[5]*linv,  acc[6]*linv,  acc[7]*linv);
    *(float4*)(ob + 8)  = make_float4(acc[8]*linv,  acc[9]*linv,  acc[10]*linv, acc[11]*linv);
    *(float4*)(ob + 12) = make_float4(acc[12]*linv, acc[13]*linv, acc[14]*linv, acc[15]*linv);
}

// ---------------------------------------------------------------- SiLU helpers
__device__ __forceinline__ float silu_f(float x) { return x / (1.0f + __expf(-x)); }

__global__ __launch_bounds__(256) void silu_mul_k(const float* __restrict__ a,
        const float* __restrict__ b, float* __restrict__ o, int n4)
{
    int i = blockIdx.x * 256 + threadIdx.x;
    if (i >= n4) return;
    float4 av = ((const float4*)a)[i], bv = ((const float4*)b)[i];
    ((float4*)o)[i] = make_float4(silu_f(av.x)*bv.x, silu_f(av.y)*bv.y,
                                  silu_f(av.z)*bv.z, silu_f(av.w)*bv.w);
}

__global__ __launch_bounds__(256) void moe_silu_k(float* __restrict__ g,
        const float* __restrict__ u, const float* __restrict__ wt_list)
{
    int slot = blockIdx.x;
    float wt = wt_list[slot];
    int i = threadIdx.x;
    float4 gv = ((const float4*)(g + (size_t)slot * Fn))[i];
    float4 uv = ((const float4*)(u + (size_t)slot * Fn))[i];
    ((float4*)(g + (size_t)slot * Fn))[i] =
        make_float4(silu_f(gv.x)*uv.x*wt, silu_f(gv.y)*uv.y*wt,
                    silu_f(gv.z)*uv.z*wt, silu_f(gv.w)*uv.w*wt);
}

// ---------------------------------------------------------------- router / top-2
__global__ __launch_bounds__(256) void router_k(const float* __restrict__ h,
        const float* __restrict__ gw, const float* __restrict__ gb,
        int* __restrict__ top_idx, float* __restrict__ top_wt, int* __restrict__ counts)
{
    int t = blockIdx.x, tid = threadIdx.x;
    int e = tid & 15, chunk = tid >> 4;
    const float* hr = h + (size_t)t * Dn;
    float part = 0.0f;
    for (int d = chunk * 128; d < chunk * 128 + 128; ++d)
        part += hr[d] * gw[d * NEXP + e];
    __shared__ float red[256];
    red[tid] = part;
    __syncthreads();
    for (int s = 128; s >= 16; s >>= 1) {
        if (tid < s) red[tid] += red[tid + s];
        __syncthreads();
    }
    if (tid == 0) {
        float lg[NEXP], mx = -1e30f;
        for (int j = 0; j < NEXP; ++j) { lg[j] = red[j]; mx = fmaxf(mx, lg[j]); }
        float se = 0.0f;
        for (int j = 0; j < NEXP; ++j) { lg[j] = __expf(lg[j] - mx); se += lg[j]; }
        float inv = 1.0f / se;
        float probs[NEXP], sel[NEXP];
        for (int j = 0; j < NEXP; ++j) { probs[j] = lg[j] * inv; sel[j] = probs[j] + gb[j]; }
        int i0 = 0; float b0 = sel[0];
        for (int j = 1; j < NEXP; ++j) if (sel[j] > b0) { b0 = sel[j]; i0 = j; }
        int i1 = -1; float b1 = -1e30f;
        for (int j = 0; j < NEXP; ++j) if (j != i0 && sel[j] > b1) { b1 = sel[j]; i1 = j; }
        float w0 = probs[i0], w1 = probs[i1];
        float wsn = 1.0f / (w0 + w1);
        top_idx[t*2] = i0; top_idx[t*2+1] = i1;
        top_wt[t*2] = w0 * wsn; top_wt[t*2+1] = w1 * wsn;
        atomicAdd(&counts[i0], 1); atomicAdd(&counts[i1], 1);
    }
}

__global__ void zero_k(int* __restrict__ counts)
{
    if (threadIdx.x < NEXP) counts[threadIdx.x] = 0;
}

__global__ void prefix_k(const int* __restrict__ counts, int* __restrict__ offsets,
                         int* __restrict__ cursor)
{
    if (threadIdx.x == 0) {
        int a = 0;
        for (int e2 = 0; e2 < NEXP; ++e2) { offsets[e2] = a; a += counts[e2]; cursor[e2] = 0; }
        offsets[NEXP] = a;
    }
}

__global__ __launch_bounds__(256) void scatter_k(const int* __restrict__ top_idx,
        const float* __restrict__ top_wt, const int* __restrict__ offsets,
        int* __restrict__ cursor, int* __restrict__ tok_list, float* __restrict__ wt_list)
{
    int t = blockIdx.x * 256 + threadIdx.x;
    if (t >= Tn) return;
    for (int k = 0; k < 2; ++k) {
        int e = top_idx[t*2 + k];
        int p = atomicAdd(&cursor[e], 1);
        int s = offsets[e] + p;
        tok_list[s] = t;
        wt_list[s] = top_wt[t*2 + k];
    }
}

// ---------------------------------------------------------------- MoE GEMMs (fp32, unchanged this round)
__global__ __launch_bounds__(256) void moe_up_k(const float* __restrict__ h,
        const float* __restrict__ W, const int* __restrict__ counts,
        const int* __restrict__ offsets, const int* __restrict__ tok_list,
        float* __restrict__ Cb)
{
    const int BM = 64, BN = 64, BK = 16;
    int e = blockIdx.z;
    int cnt = counts[e];
    int bm0 = blockIdx.y * BM;
    if (bm0 >= cnt) return;
    int off = offsets[e];
    int bn0 = blockIdx.x * BN;
    const float* B = W + (size_t)e * Dn * Fn;
    __shared__ float sA[BK][BM + 1];
    __shared__ float sB[BK][BN + 4];
    int tid = threadIdx.x;
    int tx = tid & 15, ty = tid >> 4;
    int ar = tid >> 2, ac = (tid & 3) * 4;
    int br = tid >> 4, bc = (tid & 15) * 4;
    int arow = bm0 + ar; if (arow >= cnt) arow = cnt - 1;
    int tok = tok_list[off + arow];
    const float* Ap = h + (size_t)tok * Dn + ac;
    const float* Bp = B + (size_t)br * Fn + bn0 + bc;
    float acc[4][4] = {};
    for (int kt = 0; kt < Dn; kt += BK) {
        float4 a4 = *(const float4*)(Ap + kt);
        float4 b4 = *(const float4*)(Bp + (size_t)kt * Fn);
        sA[ac + 0][ar] = a4.x; sA[ac + 1][ar] = a4.y;
        sA[ac + 2][ar] = a4.z; sA[ac + 3][ar] = a4.w;
        *(float4*)&sB[br][bc] = b4;
        __syncthreads();
        #pragma unroll
        for (int k = 0; k < BK; ++k) {
            float a0 = sA[k][ty*4+0], a1 = sA[k][ty*4+1];
            float a2 = sA[k][ty*4+2], a3 = sA[k][ty*4+3];
            float4 b = *(float4*)&sB[k][tx*4];
            acc[0][0] += a0*b.x; acc[0][1] += a0*b.y; acc[0][2] += a0*b.z; acc[0][3] += a0*b.w;
            acc[1][0] += a1*b.x; acc[1][1] += a1*b.y; acc[1][2] += a1*b.z; acc[1][3] += a1*b.w;
            acc[2][0] += a2*b.x; acc[2][1] += a2*b.y; acc[2][2] += a2*b.z; acc[2][3] += a2*b.w;
            acc[3][0] += a3*b.x; acc[3][1] += a3*b.y; acc[3][2] += a3*b.z; acc[3][3] += a3*b.w;
        }
        __syncthreads();
    }
    #pragma unroll
    for (int i = 0; i < 4; ++i) {
        int r = ty*4 + i;
        if (bm0 + r < cnt) {
            float* cp = Cb + (size_t)(off + bm0 + r) * Fn + bn0 + tx*4;
            cp[0] = acc[i][0]; cp[1] = acc[i][1]; cp[2] = acc[i][2]; cp[3] = acc[i][3];
        }
    }
}

__global__ __launch_bounds__(256) void moe_down_k(const float* __restrict__ act,
        const float* __restrict__ W2, const int* __restrict__ counts,
        const int* __restrict__ offsets, const int* __restrict__ tok_list,
        float* __restrict__ out)
{
    const int BM = 64, BN = 64, BK = 16;
    int e = blockIdx.z;
    int cnt = counts[e];
    int bm0 = blockIdx.y * BM;
    if (bm0 >= cnt) return;
    int off = offsets[e];
    int bn0 = blockIdx.x * BN;
    const float* B = W2 + (size_t)e * Fn * Dn;
    __shared__ float sA[BK][BM + 1];
    __shared__ float sB[BK][BN + 4];
    int tid = threadIdx.x;
    int tx = tid & 15, ty = tid >> 4;
    int ar = tid >> 2, ac = (tid & 3) * 4;
    int br = tid >> 4, bc = (tid & 15) * 4;
    int arow = bm0 + ar; if (arow >= cnt) arow = cnt - 1;
    const float* Ap = act + (size_t)(off + arow) * Fn + ac;
    const float* Bp = B + (size_t)br * Dn + bn0 + bc;
    float acc[4][4] = {};
    for (int kt = 0; kt < Fn; kt += BK) {
        float4 a4 = *(const float4*)(Ap + kt);
        float4 b4 = *(const float4*)(Bp + (size_t)kt * Dn);
        sA[ac + 0][ar] = a4.x; sA[ac + 1][ar] = a4.y;
        sA[ac + 2][ar] = a4.z; sA[ac + 3][ar] = a4.w;
        *(float4*)&sB[br][bc] = b4;
        __syncthreads();
        #pragma unroll
        for (int k = 0; k < BK; ++k) {
            float a0 = sA[k][ty*4+0], a1 = sA[k][ty*4+1];
            float a2 = sA[k][ty*4+2], a3 = sA[k][ty*4+3];
            float4 b = *(float4*)&sB[k][tx*4];
            acc[0][0] += a0*b.x; acc[0][1] += a0*b.y; acc[0][2] += a0*b.z; acc[0][3] += a0*b.w;
            acc[1][0] += a1*b.x; acc[1][1] += a1*b.y; acc[1][2] += a1*b.z; acc[1][3] += a1*b.w;
            acc[2][0] += a2*b.x; acc[2][1] += a2*b.y; acc[2][2] += a2*b.z; acc[2][3] += a2*b.w;
            acc[3][0] += a3*b.x; acc[3][1] += a3*b.y; acc[3][2] += a3*b.z; acc[3][3] += a3*b.w;
        }
        __syncthreads();
    }
    #pragma unroll
    for (int i = 0; i < 4; ++i) {
        int r = ty*4 + i;
        if (bm0 + r < cnt) {
            int tok = tok_list[off + bm0 + r];
            float* op = out + (size_t)tok * Dn + bn0 + tx*4;
            atomicAdd(op + 0, acc[i][0]); atomicAdd(op + 1, acc[i][1]);
            atomicAdd(op + 2, acc[i][2]); atomicAdd(op + 3, acc[i][3]);
        }
    }
}

// ---------------------------------------------------------------- launch
extern "C" void kernel_launch(void* const* d_in, const int* in_sizes, int n_in,
                              void* d_out, int out_size, void* d_ws, size_t ws_size,
                              hipStream_t stream)
{
    (void)in_sizes; (void)n_in; (void)out_size; (void)ws_size;
    const int*   positions = (const int*)d_in[0];
    const float* hidden    = (const float*)d_in[1];
    const float* w_norm1   = (const float*)d_in[3];
    const float* w_norm2   = (const float*)d_in[4];
    const float* wqkv      = (const float*)d_in[5];
    const float* wo        = (const float*)d_in[6];
    const float* gate_w    = (const float*)d_in[7];
    const float* gate_bias = (const float*)d_in[8];
    const float* w1        = (const float*)d_in[9];
    const float* w3        = (const float*)d_in[10];
    const float* w2        = (const float*)d_in[11];
    const float* ws1       = (const float*)d_in[12];
    const float* ws3       = (const float*)d_in[13];
    const float* ws2       = (const float*)d_in[14];
    float* out = (float*)d_out;

    float* ws    = (float*)d_ws;
    float* qkv   = ws;                              // T*4096 ; reused as t1|t2
    float* xr    = qkv   + (size_t)Tn * QKVN;       // T*D    ; reused as h
    float* attnb = xr    + (size_t)Tn * Dn;         // T*D    ; reused as actG
    float* x2    = attnb + (size_t)Tn * Dn;         // T*D    ; reused as actU
    float* smallb = x2   + (size_t)Tn * Dn;
    float* t1 = qkv;
    float* t2 = qkv + (size_t)Tn * FSn;
    float* h  = xr;
    float* actG = attnb;
    float* actU = x2;
    int*   top_idx = (int*)smallb;                  // 2T
    float* top_wt  = (float*)(top_idx + 2*Tn);      // 2T
    int*   counts  = (int*)(top_wt + 2*Tn);         // 16
    int*   offsets = counts + NEXP;                 // 17
    int*   cursor  = offsets + NEXP + 1;            // 16
    int*   tok_list = cursor + NEXP;                // 2T
    float* wt_list  = (float*)(tok_list + 2*Tn);    // 2T
    // bf16 hi/lo scratch (after small region; 128KB clearance keeps alignment)
    u16* Ahb = (u16*)(smallb + 32768);              // [2048,2048] bf16
    u16* Alb = Ahb + (size_t)Tn * Dn;
    u16* Bhb = Alb + (size_t)Tn * Dn;               // B^T [2048,2048] bf16
    u16* Blb = Bhb + (size_t)2048 * 2048;

    const int CV = (Tn * Dn / 4 + 255) / 256;
    dim3 g128(16, 16);      // (N/128, M/128) — all dense GEMMs are 2048x2048 here
    dim3 gt(64, 64);        // (N/32, K/32)   — transpose-convert tiles

    zero_k<<<1, 64, 0, stream>>>(counts);
    rmsnorm_k<<<Tn, 256, 0, stream>>>(hidden, w_norm1, xr);
    // ---- qkv = xr @ wqkv  (two N=2048 column halves to cap B^T scratch)
    cvt_k<<<CV, 256, 0, stream>>>(xr, Ahb, Alb, Tn*Dn/4);
    for (int hf = 0; hf < 2; ++hf) {
        cvt_t_k<<<gt, 256, 0, stream>>>(wqkv + hf*2048, Bhb, Blb, Dn, QKVN);
        gemm_mfma_k<false><<<g128, 256, 0, stream>>>(Ahb, Alb, Bhb, Blb, nullptr,
                qkv + hf*2048, Dn, QKVN);
    }
    rope_k<<<dim3(Tn, HQn + HKVn), 64, 0, stream>>>(qkv, positions);
    attn_k<<<dim3(Tn/QT, HQn), 256, 0, stream>>>(qkv, attnb);
    // ---- x2 = hidden + attnb @ wo
    cvt_k<<<CV, 256, 0, stream>>>(attnb, Ahb, Alb, Tn*Dn/4);
    cvt_t_k<<<gt, 256, 0, stream>>>(wo, Bhb, Blb, Dn, Dn);
    gemm_mfma_k<true><<<g128, 256, 0, stream>>>(Ahb, Alb, Bhb, Blb, hidden, x2, Dn, Dn);
    rmsnorm_k<<<Tn, 256, 0, stream>>>(x2, w_norm2, h);
    // ---- shared MLP: t1 = h@ws1, t2 = h@ws3, silu, out = x2 + t1@ws2
    cvt_k<<<CV, 256, 0, stream>>>(h, Ahb, Alb, Tn*Dn/4);
    cvt_t_k<<<gt, 256, 0, stream>>>(ws1, Bhb, Blb, Dn, FSn);
    gemm_mfma_k<false><<<g128, 256, 0, stream>>>(Ahb, Alb, Bhb, Blb, nullptr, t1, Dn, FSn);
    cvt_t_k<<<gt, 256, 0, stream>>>(ws3, Bhb, Blb, Dn, FSn);
    gemm_mfma_k<false><<<g128, 256, 0, stream>>>(Ahb, Alb, Bhb, Blb, nullptr, t2, Dn, FSn);
    silu_mul_k<<<(Tn*FSn/4 + 255)/256, 256, 0, stream>>>(t1, t2, t1, Tn*FSn/4);
    cvt_k<<<CV, 256, 0, stream>>>(t1, Ahb, Alb, Tn*FSn/4);
    cvt_t_k<<<gt, 256, 0, stream>>>(ws2, Bhb, Blb, FSn, Dn);
    gemm_mfma_k<true><<<g128, 256, 0, stream>>>(Ahb, Alb, Bhb, Blb, x2, out, FSn, Dn);
    // ---- MoE (fp32 path, unchanged this round)
    router_k<<<Tn, 256, 0, stream>>>(h, gate_w, gate_bias, top_idx, top_wt, counts);
    prefix_k<<<1, 64, 0, stream>>>(counts, offsets, cursor);
    scatter_k<<<Tn/256, 256, 0, stream>>>(top_idx, top_wt, offsets, cursor, tok_list, wt_list);
    moe_up_k<<<dim3(Fn/64, Tn/64, NEXP), 256, 0, stream>>>(h, w1, counts, offsets, tok_list, actG);
    moe_up_k<<<dim3(Fn/64, Tn/64, NEXP), 256, 0, stream>>>(h, w3, counts, offsets, tok_list, actU);
    moe_silu_k<<<2*Tn, 256, 0, stream>>>(actG, actU, wt_list);
    moe_down_k<<<dim3(Dn/64, Tn/64, NEXP), 256, 0, stream>>>(actG, w2, counts, offsets, tok_list, out);
}